// Round 3
// baseline (455.754 us; speedup 1.0000x reference)
//
#include <hip/hip_runtime.h>
#include <math.h>

// Problem constants
constexpr int kB  = 64;
constexpr int kT  = 2048;
constexpr int kE  = 512;
constexpr int kR  = 1024;
constexpr int kH  = 8;
constexpr int kHD = 16;
constexpr int kNF = 32;
constexpr int kKS = 31;
constexpr float kScale = 0.25f;          // 1/sqrt(16)
constexpr float kCplx  = 0.1f;
constexpr int kChunks = 16;              // t-chunks per b (128 t each)

// Workspace layout (float offsets)
constexpr size_t OFF_WQE  = 0;                            // [B,H,E]     32768
constexpr size_t OFF_CQ   = OFF_WQE + kB * kH * kE;       // [B,H]       512
constexpr size_t OFF_KEFF = OFF_CQ + kB * kH;             // [B,H,2*KS]  31744
constexpr size_t OFF_SC   = OFF_KEFF + kB * kH * 2 * kKS; // [B,T,H] exp 1048576
constexpr size_t OFF_PART = OFF_SC + (size_t)kB * kT * kH;   // [B,16,H,E] 4194304
constexpr size_t OFF_ZP   = OFF_PART + (size_t)kB * kChunks * kH * kE; // [B,16,H] 8192

__device__ __forceinline__ float bcast_lane(float v, int lane) {
    return __uint_as_float((unsigned)__builtin_amdgcn_readlane((int)__float_as_uint(v), lane));
}
// DPP cross-lane (VALU pipe, no LDS latency): quad_perm xor1 / xor2
__device__ __forceinline__ float dpp_xor1(float x) {
    return __int_as_float(__builtin_amdgcn_update_dpp(
        0, __float_as_int(x), 0xB1, 0xF, 0xF, true));   // quad_perm [1,0,3,2]
}
__device__ __forceinline__ float dpp_xor2(float x) {
    return __int_as_float(__builtin_amdgcn_update_dpp(
        0, __float_as_int(x), 0x4E, 0xF, 0xF, true));   // quad_perm [2,3,0,1]
}
// ds_swizzle BitMode xor within 32-lane halves
__device__ __forceinline__ float swz_xor4(float x) {
    return __int_as_float(__builtin_amdgcn_ds_swizzle(__float_as_int(x), 0x101F));
}
__device__ __forceinline__ float swz_xor8(float x) {
    return __int_as_float(__builtin_amdgcn_ds_swizzle(__float_as_int(x), 0x201F));
}
__device__ __forceinline__ float swz_xor16(float x) {
    return __int_as_float(__builtin_amdgcn_ds_swizzle(__float_as_int(x), 0x401F));
}

// ---------------------------------------------------------------------------
// P: per (b,h) fold query through all weight paths (Wq -> Wk/bk/Wl/conv).
// grid = B*H, block = 256
__global__ __launch_bounds__(256) void k_prep(
    const float* __restrict__ query, const float* __restrict__ Wq,
    const float* __restrict__ bq, const float* __restrict__ Wk,
    const float* __restrict__ bk, const float* __restrict__ Wl,
    const float* __restrict__ convw,
    float* __restrict__ wqe, float* __restrict__ cq, float* __restrict__ keff) {
    int bh = blockIdx.x;
    int b = bh >> 3, h = bh & 7;
    int tid = threadIdx.x;

    __shared__ float q_s[16 * 65];       // padded: kills 16-way bank conflict
    __shared__ float part[kHD][17];
    __shared__ float qd[kHD];
    __shared__ float wl_s[kNF];

    for (int i = tid; i < kR; i += 256)
        q_s[(i >> 6) * 65 + (i & 63)] = query[(size_t)b * kR + i];
    __syncthreads();

    {
        int d = tid >> 4, p = tid & 15;
        const float* wrow = Wq + (size_t)(h * kHD + d) * kR + p * 64;
        const float* qrow = q_s + p * 65;
        float pa = 0.f;
        #pragma unroll 8
        for (int i = 0; i < 64; ++i) pa += wrow[i] * qrow[i];
        part[d][p] = pa;
    }
    __syncthreads();
    if (tid < kHD) {
        float acc = bq[h * kHD + tid];
        #pragma unroll
        for (int p = 0; p < 16; ++p) acc += part[tid][p];
        qd[tid] = acc;
    }
    __syncthreads();

    for (int e = tid; e < kE; e += 256) {
        float acc = 0.f;
        #pragma unroll
        for (int d = 0; d < kHD; ++d) acc += qd[d] * Wk[(size_t)(h * kHD + d) * kE + e];
        wqe[(size_t)bh * kE + e] = acc;
    }
    if (tid < kNF) {
        float acc = 0.f;
        #pragma unroll
        for (int d = 0; d < kHD; ++d) acc += qd[d] * Wl[(h * kHD + d) * kNF + tid];
        wl_s[tid] = acc;
    }
    if (tid == 0) {
        float acc = 0.f;
        #pragma unroll
        for (int d = 0; d < kHD; ++d) acc += qd[d] * bk[h * kHD + d];
        cq[bh] = acc;
    }
    __syncthreads();
    if (tid < 2 * kKS) {
        float acc = 0.f;
        #pragma unroll
        for (int f = 0; f < kNF; ++f) acc += wl_s[f] * convw[f * 2 * kKS + tid];
        keff[bh * 2 * kKS + tid] = acc;
    }
}

// ---------------------------------------------------------------------------
// S: fused scores + exp + per-chunk context partials. ONE pass over memory.
// Head-split waves: 4 waves = 2 pairs; pair p owns rows t0+64p..+63, the two
// waves of a pair own head groups hg=0..3 / 4..7 (halves register arrays ->
// 3 blocks/CU at launch_bounds(256,3); pair-partner's duplicate row read is
// an L1 hit, HBM traffic unchanged).
// grid = (16, B), block = 256.
__global__ __launch_bounds__(256, 3) void k_scores(
    const float* __restrict__ mem, const float* __restrict__ awc,
    const float* __restrict__ wqe, const float* __restrict__ cq,
    const float* __restrict__ keff, float* __restrict__ sc,
    float* __restrict__ part, float* __restrict__ zp) {
    constexpr int WIN = 128 + kKS - 1;   // 158
    int b = blockIdx.y;
    int blk = blockIdx.x;
    int t0 = blk * 128;
    int tid = threadIdx.x;
    int wave = tid >> 6, lane = tid & 63;
    int p = wave >> 1;                   // row-group pair (0,1)
    int q = wave & 1;                    // head half
    int hg = q << 2;                     // 0 or 4

    __shared__ float aw[2][WIN];
    __shared__ float ke[kH][2 * kKS];
    __shared__ float cq_s[kH];
    __shared__ float loc_s[128][9];          // +1 pad
    __shared__ float obh_s[kH][kE];          // 16 KB block accumulator
    __shared__ float zp_s[4][4];

    for (int i = tid; i < 2 * WIN; i += 256) {
        int c = i / WIN, j = i % WIN;
        int t = t0 - (kKS - 1) / 2 + j;
        aw[c][j] = (t >= 0 && t < kT) ? awc[((size_t)b * 2 + c) * kT + t] : 0.f;
    }
    for (int i = tid; i < kH * 2 * kKS; i += 256)
        ke[i / (2 * kKS)][i % (2 * kKS)] = keff[(size_t)b * kH * 2 * kKS + i];
    if (tid < kH) cq_s[tid] = cq[b * kH + tid];
    for (int i = tid; i < kH * kE; i += 256) ((float*)obh_s)[i] = 0.f;
    __syncthreads();

    // location FIR: all 256 threads (t = tid&127, head-half = tid>>7)
    {
        int tt = tid & 127;
        int fg = (tid >> 7) << 2;            // 0 or 4
        float a0 = 0.f, a1 = 0.f, a2 = 0.f, a3 = 0.f;
        #pragma unroll
        for (int c = 0; c < 2; ++c) {
            #pragma unroll
            for (int k = 0; k < kKS; ++k) {
                float a = aw[c][tt + k];
                a0 += ke[fg + 0][c * kKS + k] * a;
                a1 += ke[fg + 1][c * kKS + k] * a;
                a2 += ke[fg + 2][c * kKS + k] * a;
                a3 += ke[fg + 3][c * kKS + k] * a;
            }
        }
        loc_s[tt][fg + 0] = a0;
        loc_s[tt][fg + 1] = a1;
        loc_s[tt][fg + 2] = a2;
        loc_s[tt][fg + 3] = a3;
    }

    // per-wave content weights for its 4 heads:
    // lane holds e = 4*lane..+3 and 256+4*lane..+3
    float w[4][8];
    {
        const float* wq_b = wqe + (size_t)b * kH * kE;
        #pragma unroll
        for (int i = 0; i < 4; ++i) {
            const float4* pw = (const float4*)(wq_b + (hg + i) * kE);
            float4 x = pw[lane];
            float4 y = pw[64 + lane];
            w[i][0] = x.x; w[i][1] = x.y; w[i][2] = x.z; w[i][3] = x.w;
            w[i][4] = y.x; w[i][5] = y.y; w[i][6] = y.z; w[i][7] = y.w;
        }
    }
    float acc[4][8];
    #pragma unroll
    for (int i = 0; i < 4; ++i)
        #pragma unroll
        for (int j = 0; j < 8; ++j) acc[i][j] = 0.f;
    float zacc = 0.f;
    __syncthreads();

    // main loop: pair p covers 64 rows; 2 rows/iter + next-pair prefetch.
    const float4* m4 = (const float4*)(mem + ((size_t)b * kT + t0 + p * 64) * kE);
    float4 x0 = m4[lane],        y0 = m4[64 + lane];
    float4 x1 = m4[128 + lane],  y1 = m4[192 + lane];
    for (int r = 0; r < 64; r += 2) {
        const float4* mn = m4 + ((r + 2) & 63) * 128;   // wrap on last iter
        float4 nx0 = mn[lane],       ny0 = mn[64 + lane];
        float4 nx1 = mn[128 + lane], ny1 = mn[192 + lane];

        float v0[4], v1[4];
        #pragma unroll
        for (int i = 0; i < 4; ++i) {
            v0[i] = x0.x * w[i][0] + x0.y * w[i][1] + x0.z * w[i][2] + x0.w * w[i][3]
                  + y0.x * w[i][4] + y0.y * w[i][5] + y0.z * w[i][6] + y0.w * w[i][7];
            v1[i] = x1.x * w[i][0] + x1.y * w[i][1] + x1.z * w[i][2] + x1.w * w[i][3]
                  + y1.x * w[i][4] + y1.y * w[i][5] + y1.z * w[i][6] + y1.w * w[i][7];
        }
        // scatter-reduce 4->2->1: xor1, xor2 via DPP (VALU pipe)
        {
            int bit = lane & 1;
            #pragma unroll
            for (int i = 0; i < 2; ++i) {
                float k0 = v0[2 * i + bit], o0 = v0[2 * i + (1 - bit)];
                v0[i] = k0 + dpp_xor1(o0);
                float k1 = v1[2 * i + bit], o1 = v1[2 * i + (1 - bit)];
                v1[i] = k1 + dpp_xor1(o1);
            }
        }
        {
            int bit = (lane >> 1) & 1;
            float k0 = v0[bit], o0 = v0[1 - bit];
            v0[0] = k0 + dpp_xor2(o0);
            float k1 = v1[bit], o1 = v1[1 - bit];
            v1[0] = k1 + dpp_xor2(o1);
        }
        float r0 = v0[0], r1 = v1[0];
        r0 += swz_xor4(r0);          r1 += swz_xor4(r1);
        r0 += swz_xor8(r0);          r1 += swz_xor8(r1);
        r0 += swz_xor16(r0);         r1 += swz_xor16(r1);
        r0 += __shfl_xor(r0, 32, 64);
        r1 += __shfl_xor(r1, 32, 64);
        // every lane now holds the full sum for head hg + (lane&3)
        int hh = hg + (lane & 3);
        int wr = p * 64 + r;
        float s0 = kScale * (r0 + cq_s[hh] + kCplx * loc_s[wr][hh]);
        float s1 = kScale * (r1 + cq_s[hh] + kCplx * loc_s[wr + 1][hh]);
        float ex0 = __expf(s0);
        float ex1 = __expf(s1);
        if (lane < 4) {
            size_t tbase = ((size_t)b * kT + t0 + wr) * kH + hg;
            sc[tbase + lane] = ex0;
            sc[tbase + kH + lane] = ex1;
        }
        zacc += ex0 + ex1;           // 16 copies per head; one stored below
        #pragma unroll
        for (int i = 0; i < 4; ++i) {
            float pa = bcast_lane(ex0, i);
            float pb = bcast_lane(ex1, i);
            acc[i][0] += pa * x0.x; acc[i][1] += pa * x0.y;
            acc[i][2] += pa * x0.z; acc[i][3] += pa * x0.w;
            acc[i][4] += pa * y0.x; acc[i][5] += pa * y0.y;
            acc[i][6] += pa * y0.z; acc[i][7] += pa * y0.w;
            acc[i][0] += pb * x1.x; acc[i][1] += pb * x1.y;
            acc[i][2] += pb * x1.z; acc[i][3] += pb * x1.w;
            acc[i][4] += pb * y1.x; acc[i][5] += pb * y1.y;
            acc[i][6] += pb * y1.z; acc[i][7] += pb * y1.w;
        }
        x0 = nx0; y0 = ny0; x1 = nx1; y1 = ny1;
    }
    if (lane < 4) zp_s[wave][lane] = zacc;

    // two rounds over row-group pairs; within a round the two active waves
    // write disjoint head rows (hg 0..3 vs 4..7), lanes cover disjoint e.
    for (int pp = 0; pp < 2; ++pp) {
        __syncthreads();
        if (p == pp) {
            #pragma unroll
            for (int i = 0; i < 4; ++i) {
                int h = hg + i;
                obh_s[h][4 * lane + 0] += acc[i][0];
                obh_s[h][4 * lane + 1] += acc[i][1];
                obh_s[h][4 * lane + 2] += acc[i][2];
                obh_s[h][4 * lane + 3] += acc[i][3];
                obh_s[h][256 + 4 * lane + 0] += acc[i][4];
                obh_s[h][256 + 4 * lane + 1] += acc[i][5];
                obh_s[h][256 + 4 * lane + 2] += acc[i][6];
                obh_s[h][256 + 4 * lane + 3] += acc[i][7];
            }
        }
    }
    __syncthreads();

    float* pdst = part + ((size_t)(b * kChunks + blk) * kH) * kE;
    for (int i = tid; i < kH * kE; i += 256) pdst[i] = ((float*)obh_s)[i];
    if (tid < kH) {
        int qq = tid >> 2, ii = tid & 3;
        float z = zp_s[qq][ii] + zp_s[2 + qq][ii];
        zp[(size_t)(b * kChunks + blk) * kH + tid] = z;
    }
}

// ---------------------------------------------------------------------------
// F: finalize. Z_h = sum_blk zp; context[b,e] = (1/8) sum_h O_h[e]/Z_h;
//    fw[b,t] = (1/8) sum_h sc[b,t,h]/Z_h.
// grid = (5, B): sec 0 -> ctx, sec 1..4 -> fw quarter (512 t each).
__global__ __launch_bounds__(256) void k_final(
    const float* __restrict__ part, const float* __restrict__ zp,
    const float* __restrict__ sc, float* __restrict__ ctx,
    float* __restrict__ fw) {
    int b = blockIdx.y, sec = blockIdx.x, tid = threadIdx.x;
    __shared__ float rz_s[kH];
    if (tid < kH) {
        float z = 0.f;
        for (int blk = 0; blk < kChunks; ++blk)
            z += zp[(size_t)(b * kChunks + blk) * kH + tid];
        rz_s[tid] = 1.f / z;
    }
    __syncthreads();

    if (sec == 0) {
        const float* pb = part + (size_t)b * kChunks * kH * kE;
        #pragma unroll
        for (int i = 0; i < 2; ++i) {
            int e = tid + i * 256;
            float s = 0.f;
            #pragma unroll
            for (int h = 0; h < kH; ++h) {
                float oh = 0.f;
                for (int blk = 0; blk < kChunks; ++blk)
                    oh += pb[((size_t)blk * kH + h) * kE + e];
                s += oh * rz_s[h];
            }
            ctx[(size_t)b * kE + e] = 0.125f * s;
        }
    } else {
        int tb = (sec - 1) * 512;
        #pragma unroll
        for (int i = 0; i < 2; ++i) {
            int t = tb + tid + i * 256;
            const float4* pp = (const float4*)(sc + ((size_t)b * kT + t) * kH);
            float4 x = pp[0], y = pp[1];
            float f = x.x * rz_s[0] + x.y * rz_s[1] + x.z * rz_s[2] + x.w * rz_s[3]
                    + y.x * rz_s[4] + y.y * rz_s[5] + y.z * rz_s[6] + y.w * rz_s[7];
            fw[(size_t)b * kT + t] = 0.125f * f;
        }
    }
}

// ---------------------------------------------------------------------------
extern "C" void kernel_launch(void* const* d_in, const int* in_sizes, int n_in,
                              void* d_out, int out_size, void* d_ws, size_t ws_size,
                              hipStream_t stream) {
    const float* query = (const float*)d_in[0];
    const float* mem   = (const float*)d_in[1];
    const float* awc   = (const float*)d_in[3];
    const float* Wq    = (const float*)d_in[5];
    const float* bq    = (const float*)d_in[6];
    const float* Wk    = (const float*)d_in[7];
    const float* bk    = (const float*)d_in[8];
    const float* convw = (const float*)d_in[13];
    const float* Wl    = (const float*)d_in[14];

    float* ws   = (float*)d_ws;
    float* wqe  = ws + OFF_WQE;
    float* cq   = ws + OFF_CQ;
    float* keff = ws + OFF_KEFF;
    float* sc   = ws + OFF_SC;
    float* part = ws + OFF_PART;
    float* zp   = ws + OFF_ZP;

    float* ctx = (float*)d_out;                 // [B,E]
    float* fw  = (float*)d_out + kB * kE;       // [B,T]

    k_prep<<<kB * kH, 256, 0, stream>>>(query, Wq, bq, Wk, bk, Wl, convw, wqe, cq, keff);
    k_scores<<<dim3(kChunks, kB), 256, 0, stream>>>(mem, awc, wqe, cq, keff, sc, part, zp);
    k_final<<<dim3(5, kB), 256, 0, stream>>>(part, zp, sc, ctx, fw);
}

// Round 4
// 442.731 us; speedup vs baseline: 1.0294x; 1.0294x over previous
//
#include <hip/hip_runtime.h>
#include <math.h>

// Problem constants
constexpr int kB  = 64;
constexpr int kT  = 2048;
constexpr int kE  = 512;
constexpr int kR  = 1024;
constexpr int kH  = 8;
constexpr int kHD = 16;
constexpr int kNF = 32;
constexpr int kKS = 31;
constexpr float kScale = 0.25f;          // 1/sqrt(16)
constexpr float kCplx  = 0.1f;
constexpr int kChunks = 8;               // t-chunks per b (256 t each) -> 512 blocks = exactly 2/CU

// Workspace layout (float offsets)
constexpr size_t OFF_WQE  = 0;                            // [B,H,E]     32768
constexpr size_t OFF_CQ   = OFF_WQE + kB * kH * kE;       // [B,H]       512
constexpr size_t OFF_KEFF = OFF_CQ + kB * kH;             // [B,H,2*KS]  31744
constexpr size_t OFF_SC   = OFF_KEFF + kB * kH * 2 * kKS; // [B,T,H] exp 1048576
constexpr size_t OFF_PART = OFF_SC + (size_t)kB * kT * kH;   // [B,8,H,E]
constexpr size_t OFF_ZP   = OFF_PART + (size_t)kB * kChunks * kH * kE; // [B,8,H]

__device__ __forceinline__ float bcast_lane(float v, int lane) {
    return __uint_as_float((unsigned)__builtin_amdgcn_readlane((int)__float_as_uint(v), lane));
}

// ---------------------------------------------------------------------------
// P: per (b,h) fold query through all weight paths (Wq -> Wk/bk/Wl/conv).
// grid = B*H, block = 256
__global__ __launch_bounds__(256) void k_prep(
    const float* __restrict__ query, const float* __restrict__ Wq,
    const float* __restrict__ bq, const float* __restrict__ Wk,
    const float* __restrict__ bk, const float* __restrict__ Wl,
    const float* __restrict__ convw,
    float* __restrict__ wqe, float* __restrict__ cq, float* __restrict__ keff) {
    int bh = blockIdx.x;
    int b = bh >> 3, h = bh & 7;
    int tid = threadIdx.x;

    __shared__ float q_s[16 * 65];       // padded: kills 16-way bank conflict
    __shared__ float part[kHD][17];
    __shared__ float qd[kHD];
    __shared__ float wl_s[kNF];

    for (int i = tid; i < kR; i += 256)
        q_s[(i >> 6) * 65 + (i & 63)] = query[(size_t)b * kR + i];
    __syncthreads();

    {
        int d = tid >> 4, p = tid & 15;
        const float* wrow = Wq + (size_t)(h * kHD + d) * kR + p * 64;
        const float* qrow = q_s + p * 65;
        float pa = 0.f;
        #pragma unroll 8
        for (int i = 0; i < 64; ++i) pa += wrow[i] * qrow[i];
        part[d][p] = pa;
    }
    __syncthreads();
    if (tid < kHD) {
        float acc = bq[h * kHD + tid];
        #pragma unroll
        for (int p = 0; p < 16; ++p) acc += part[tid][p];
        qd[tid] = acc;
    }
    __syncthreads();

    for (int e = tid; e < kE; e += 256) {
        float acc = 0.f;
        #pragma unroll
        for (int d = 0; d < kHD; ++d) acc += qd[d] * Wk[(size_t)(h * kHD + d) * kE + e];
        wqe[(size_t)bh * kE + e] = acc;
    }
    if (tid < kNF) {
        float acc = 0.f;
        #pragma unroll
        for (int d = 0; d < kHD; ++d) acc += qd[d] * Wl[(h * kHD + d) * kNF + tid];
        wl_s[tid] = acc;
    }
    if (tid == 0) {
        float acc = 0.f;
        #pragma unroll
        for (int d = 0; d < kHD; ++d) acc += qd[d] * bk[h * kHD + d];
        cq[bh] = acc;
    }
    __syncthreads();
    if (tid < 2 * kKS) {
        float acc = 0.f;
        #pragma unroll
        for (int f = 0; f < kNF; ++f) acc += wl_s[f] * convw[f * 2 * kKS + tid];
        keff[bh * 2 * kKS + tid] = acc;
    }
}

// ---------------------------------------------------------------------------
// S: fused scores + exp + per-chunk context partials. ONE pass over memory.
// Round-1 structure (each wave owns 64 rows exclusively, all 8 heads — load-
// optimal: each mem row loaded once). 256 t per block; grid = (8, B) = 512
// blocks = exactly 2 blocks/CU at launch_bounds(256,2).
__global__ __launch_bounds__(256, 2) void k_scores(
    const float* __restrict__ mem, const float* __restrict__ awc,
    const float* __restrict__ wqe, const float* __restrict__ cq,
    const float* __restrict__ keff, float* __restrict__ sc,
    float* __restrict__ part, float* __restrict__ zp) {
    constexpr int ROWS = kT / kChunks;        // 256
    constexpr int WIN = ROWS + kKS - 1;       // 286
    int b = blockIdx.y;
    int blk = blockIdx.x;
    int t0 = blk * ROWS;
    int tid = threadIdx.x;
    int wave = tid >> 6, lane = tid & 63;

    __shared__ float aw[2][WIN];
    __shared__ float ke[kH][2 * kKS];
    __shared__ float cq_s[kH];
    __shared__ float loc_s[ROWS][9];         // +1 pad
    __shared__ float obh_s[2][kH][kE];       // dual 16 KB accumulators
    __shared__ float zp_s[4][kH];

    for (int i = tid; i < 2 * WIN; i += 256) {
        int c = i / WIN, j = i % WIN;
        int t = t0 - (kKS - 1) / 2 + j;
        aw[c][j] = (t >= 0 && t < kT) ? awc[((size_t)b * 2 + c) * kT + t] : 0.f;
    }
    for (int i = tid; i < kH * 2 * kKS; i += 256)
        ke[i / (2 * kKS)][i % (2 * kKS)] = keff[(size_t)b * kH * 2 * kKS + i];
    if (tid < kH) cq_s[tid] = cq[b * kH + tid];
    for (int i = tid; i < 2 * kH * kE; i += 256) ((float*)obh_s)[i] = 0.f;
    __syncthreads();

    // location FIR: each thread handles one t (256 t), all 8 heads
    {
        int tt = tid;
        float a0 = 0.f, a1 = 0.f, a2 = 0.f, a3 = 0.f;
        float a4 = 0.f, a5 = 0.f, a6 = 0.f, a7 = 0.f;
        #pragma unroll
        for (int c = 0; c < 2; ++c) {
            #pragma unroll
            for (int k = 0; k < kKS; ++k) {
                float a = aw[c][tt + k];
                a0 += ke[0][c * kKS + k] * a;
                a1 += ke[1][c * kKS + k] * a;
                a2 += ke[2][c * kKS + k] * a;
                a3 += ke[3][c * kKS + k] * a;
                a4 += ke[4][c * kKS + k] * a;
                a5 += ke[5][c * kKS + k] * a;
                a6 += ke[6][c * kKS + k] * a;
                a7 += ke[7][c * kKS + k] * a;
            }
        }
        loc_s[tt][0] = a0; loc_s[tt][1] = a1; loc_s[tt][2] = a2; loc_s[tt][3] = a3;
        loc_s[tt][4] = a4; loc_s[tt][5] = a5; loc_s[tt][6] = a6; loc_s[tt][7] = a7;
    }

    // per-wave content weights: lane holds e = 4*lane..+3 and 256+4*lane..+3
    float w[kH][8];
    {
        const float* wq_b = wqe + (size_t)b * kH * kE;
        #pragma unroll
        for (int h = 0; h < kH; ++h) {
            const float4* p = (const float4*)(wq_b + h * kE);
            float4 x = p[lane];
            float4 y = p[64 + lane];
            w[h][0] = x.x; w[h][1] = x.y; w[h][2] = x.z; w[h][3] = x.w;
            w[h][4] = y.x; w[h][5] = y.y; w[h][6] = y.z; w[h][7] = y.w;
        }
    }
    float acc[kH][8];
    #pragma unroll
    for (int h = 0; h < kH; ++h)
        #pragma unroll
        for (int j = 0; j < 8; ++j) acc[h][j] = 0.f;
    float zacc = 0.f;
    float scv = 0.f;                 // staged sc values (8-row groups)
    __syncthreads();

    // main loop: wave owns 64 rows; 2 rows/iter + next-pair prefetch.
    const float4* m4 = (const float4*)(mem + ((size_t)b * kT + t0 + wave * 64) * kE);
    float4 x0 = m4[lane],        y0 = m4[64 + lane];
    float4 x1 = m4[128 + lane],  y1 = m4[192 + lane];
    for (int r = 0; r < 64; r += 2) {
        const float4* mn = m4 + ((r + 2) & 63) * 128;   // wrap on last iter
        float4 nx0 = mn[lane],       ny0 = mn[64 + lane];
        float4 nx1 = mn[128 + lane], ny1 = mn[192 + lane];

        float v0[kH], v1[kH];
        #pragma unroll
        for (int h = 0; h < kH; ++h) {
            v0[h] = x0.x * w[h][0] + x0.y * w[h][1] + x0.z * w[h][2] + x0.w * w[h][3]
                  + y0.x * w[h][4] + y0.y * w[h][5] + y0.z * w[h][6] + y0.w * w[h][7];
            v1[h] = x1.x * w[h][0] + x1.y * w[h][1] + x1.z * w[h][2] + x1.w * w[h][3]
                  + y1.x * w[h][4] + y1.y * w[h][5] + y1.z * w[h][6] + y1.w * w[h][7];
        }
        // scatter-reduce 8->4->2->1 over xor {1,2,4}, then butterfly 8,16,32
        #pragma unroll
        for (int s = 0; s < 3; ++s) {
            int m = 1 << s;
            int bit = (lane >> s) & 1;
            #pragma unroll
            for (int i = 0; i < (8 >> (s + 1)); ++i) {
                float k0 = v0[2 * i + bit];
                float o0 = v0[2 * i + (1 - bit)];
                v0[i] = k0 + __shfl_xor(o0, m, 64);
                float k1 = v1[2 * i + bit];
                float o1 = v1[2 * i + (1 - bit)];
                v1[i] = k1 + __shfl_xor(o1, m, 64);
            }
        }
        float r0 = v0[0], r1 = v1[0];
        r0 += __shfl_xor(r0, 8, 64);   r1 += __shfl_xor(r1, 8, 64);
        r0 += __shfl_xor(r0, 16, 64);  r1 += __shfl_xor(r1, 16, 64);
        r0 += __shfl_xor(r0, 32, 64);  r1 += __shfl_xor(r1, 32, 64);
        // every lane now holds the full sum for head (lane&7)
        int hh = lane & 7;
        int wr = wave * 64 + r;
        float s0 = kScale * (r0 + cq_s[hh] + kCplx * loc_s[wr][hh]);
        float s1 = kScale * (r1 + cq_s[hh] + kCplx * loc_s[wr + 1][hh]);
        float ex0 = __expf(s0);
        float ex1 = __expf(s1);
        // stage sc in registers: lane keeps row (lane>>3) of each 8-row group,
        // head lane&7; one fully-coalesced 256B store per group.
        scv = ((lane >> 3) == (r & 7))       ? ex0 : scv;
        scv = ((lane >> 3) == ((r + 1) & 7)) ? ex1 : scv;
        if ((r & 7) == 6) {
            size_t gbase = ((size_t)b * kT + t0 + wave * 64 + (r & ~7)) * kH;
            sc[gbase + lane] = scv;   // offset (row<<3)+head == lane
        }
        zacc += ex0 + ex1;  // lane's head = lane&7 (8 identical copies per head)
        #pragma unroll
        for (int h = 0; h < kH; ++h) {
            float pa = bcast_lane(ex0, h);
            float pb = bcast_lane(ex1, h);
            acc[h][0] += pa * x0.x; acc[h][1] += pa * x0.y;
            acc[h][2] += pa * x0.z; acc[h][3] += pa * x0.w;
            acc[h][4] += pa * y0.x; acc[h][5] += pa * y0.y;
            acc[h][6] += pa * y0.z; acc[h][7] += pa * y0.w;
            acc[h][0] += pb * x1.x; acc[h][1] += pb * x1.y;
            acc[h][2] += pb * x1.z; acc[h][3] += pb * x1.w;
            acc[h][4] += pb * y1.x; acc[h][5] += pb * y1.y;
            acc[h][6] += pb * y1.z; acc[h][7] += pb * y1.w;
        }
        x0 = nx0; y0 = ny0; x1 = nx1; y1 = ny1;
    }
    if (lane < kH) zp_s[wave][lane] = zacc;

    // dual-buffer merge: round rr has waves {rr, rr+2} active, writing to
    // disjoint buffers (wave>>1); 2 barriers instead of 4. Within a wave,
    // lanes cover disjoint e.
    for (int rr = 0; rr < 2; ++rr) {
        __syncthreads();
        if ((wave & 1) == rr) {
            float (*ob)[kE] = obh_s[wave >> 1];
            #pragma unroll
            for (int h = 0; h < kH; ++h) {
                ob[h][4 * lane + 0] += acc[h][0];
                ob[h][4 * lane + 1] += acc[h][1];
                ob[h][4 * lane + 2] += acc[h][2];
                ob[h][4 * lane + 3] += acc[h][3];
                ob[h][256 + 4 * lane + 0] += acc[h][4];
                ob[h][256 + 4 * lane + 1] += acc[h][5];
                ob[h][256 + 4 * lane + 2] += acc[h][6];
                ob[h][256 + 4 * lane + 3] += acc[h][7];
            }
        }
    }
    __syncthreads();

    float* pdst = part + ((size_t)(b * kChunks + blk) * kH) * kE;
    for (int i = tid; i < kH * kE; i += 256)
        pdst[i] = ((float*)obh_s)[i] + ((float*)obh_s)[kH * kE + i];
    if (tid < kH) {
        float z = zp_s[0][tid] + zp_s[1][tid] + zp_s[2][tid] + zp_s[3][tid];
        zp[(size_t)(b * kChunks + blk) * kH + tid] = z;
    }
}

// ---------------------------------------------------------------------------
// F: finalize. Z_h = sum_blk zp; context[b,e] = (1/8) sum_h O_h[e]/Z_h;
//    fw[b,t] = (1/8) sum_h sc[b,t,h]/Z_h.
// grid = (5, B): sec 0 -> ctx, sec 1..4 -> fw quarter (512 t each).
__global__ __launch_bounds__(256) void k_final(
    const float* __restrict__ part, const float* __restrict__ zp,
    const float* __restrict__ sc, float* __restrict__ ctx,
    float* __restrict__ fw) {
    int b = blockIdx.y, sec = blockIdx.x, tid = threadIdx.x;
    __shared__ float rz_s[kH];
    if (tid < kH) {
        float z = 0.f;
        for (int blk = 0; blk < kChunks; ++blk)
            z += zp[(size_t)(b * kChunks + blk) * kH + tid];
        rz_s[tid] = 1.f / z;
    }
    __syncthreads();

    if (sec == 0) {
        const float* pb = part + (size_t)b * kChunks * kH * kE;
        #pragma unroll
        for (int i = 0; i < 2; ++i) {
            int e = tid + i * 256;
            float s = 0.f;
            #pragma unroll
            for (int h = 0; h < kH; ++h) {
                float oh = 0.f;
                for (int blk = 0; blk < kChunks; ++blk)
                    oh += pb[((size_t)blk * kH + h) * kE + e];
                s += oh * rz_s[h];
            }
            ctx[(size_t)b * kE + e] = 0.125f * s;
        }
    } else {
        int tb = (sec - 1) * 512;
        #pragma unroll
        for (int i = 0; i < 2; ++i) {
            int t = tb + tid + i * 256;
            const float4* p = (const float4*)(sc + ((size_t)b * kT + t) * kH);
            float4 x = p[0], y = p[1];
            float f = x.x * rz_s[0] + x.y * rz_s[1] + x.z * rz_s[2] + x.w * rz_s[3]
                    + y.x * rz_s[4] + y.y * rz_s[5] + y.z * rz_s[6] + y.w * rz_s[7];
            fw[(size_t)b * kT + t] = 0.125f * f;
        }
    }
}

// ---------------------------------------------------------------------------
extern "C" void kernel_launch(void* const* d_in, const int* in_sizes, int n_in,
                              void* d_out, int out_size, void* d_ws, size_t ws_size,
                              hipStream_t stream) {
    const float* query = (const float*)d_in[0];
    const float* mem   = (const float*)d_in[1];
    const float* awc   = (const float*)d_in[3];
    const float* Wq    = (const float*)d_in[5];
    const float* bq    = (const float*)d_in[6];
    const float* Wk    = (const float*)d_in[7];
    const float* bk    = (const float*)d_in[8];
    const float* convw = (const float*)d_in[13];
    const float* Wl    = (const float*)d_in[14];

    float* ws   = (float*)d_ws;
    float* wqe  = ws + OFF_WQE;
    float* cq   = ws + OFF_CQ;
    float* keff = ws + OFF_KEFF;
    float* sc   = ws + OFF_SC;
    float* part = ws + OFF_PART;
    float* zp   = ws + OFF_ZP;

    float* ctx = (float*)d_out;                 // [B,E]
    float* fw  = (float*)d_out + kB * kE;       // [B,T]

    k_prep<<<kB * kH, 256, 0, stream>>>(query, Wq, bq, Wk, bk, Wl, convw, wqe, cq, keff);
    k_scores<<<dim3(kChunks, kB), 256, 0, stream>>>(mem, awc, wqe, cq, keff, sc, part, zp);
    k_final<<<dim3(5, kB), 256, 0, stream>>>(part, zp, sc, ctx, fw);
}